// Round 2
// baseline (419.889 us; speedup 1.0000x reference)
//
#include <hip/hip_runtime.h>

#define NB 2
#define DD 480
#define HH 360
#define WD 32
#define CIN 16
#define COUT 32
#define EPSV 1e-5f
#define NEGS 0.01f

__global__ __launch_bounds__(256) void scatter_grid(const int* __restrict__ coords,
                                                    int* __restrict__ grid, int n) {
    int i = blockIdx.x * 256 + threadIdx.x;
    if (i >= n) return;
    int b = coords[i * 4 + 0];
    int z = coords[i * 4 + 1];
    int y = coords[i * 4 + 2];
    int x = coords[i * 4 + 3];
    grid[(((size_t)b * DD + z) * HH + y) * WD + x] = i;
}

// nbr133: offsets (0,dy,dx), k = (dy+1)*3 + (dx+1)
// nbr313: offsets (dz,0,dx), k = (dz+1)*3 + (dx+1)
__global__ __launch_bounds__(256) void build_nbr(const int* __restrict__ coords,
                                                 const int* __restrict__ grid,
                                                 int* __restrict__ nbr133,
                                                 int* __restrict__ nbr313, int n) {
    int i = blockIdx.x * 256 + threadIdx.x;
    if (i >= n) return;
    int b = coords[i * 4 + 0];
    int z = coords[i * 4 + 1];
    int y = coords[i * 4 + 2];
    int x = coords[i * 4 + 3];
    size_t base_b = (size_t)b * DD;
#pragma unroll
    for (int k = 0; k < 9; ++k) {
        int d0 = k / 3 - 1;  // dy for 133, dz for 313
        int dx = k % 3 - 1;
        int nx = x + dx;
        bool xok = (nx >= 0) && (nx < WD);
        int ny = y + d0;
        int v1 = -1;
        if (xok && ny >= 0 && ny < HH)
            v1 = grid[((base_b + z) * HH + ny) * WD + nx];
        nbr133[(size_t)k * n + i] = v1;
        int nz = z + d0;
        int v2 = -1;
        if (xok && nz >= 0 && nz < DD)
            v2 = grid[((base_b + nz) * HH + y) * WD + nx];
        nbr313[(size_t)k * n + i] = v2;
    }
}

// Fused pair of independent sparse convs: blocks [0,nblk) do conv "0",
// blocks [nblk,2*nblk) do conv "1". Branch-free gathers (clamped index +
// sel-multiply) so the compiler can pipeline all 9 neighbors' loads.
template <int CI>
__global__ __launch_bounds__(256) void conv_pair(
    const float* __restrict__ in0, const int* __restrict__ nbr0,
    const float* __restrict__ Wg0, float* __restrict__ out0, int bni0,
    const float* __restrict__ in1, const int* __restrict__ nbr1,
    const float* __restrict__ Wg1, float* __restrict__ out1, int bni1,
    const float* __restrict__ gamma, const float* __restrict__ beta,
    const float* __restrict__ mean, const float* __restrict__ var,
    int n, int nblk) {
    __shared__ float Wl[9 * CI * COUT];
    __shared__ float sscale[COUT];
    __shared__ float sshift[COUT];
    int tid = threadIdx.x;
    bool second = (int)blockIdx.x >= nblk;
    const float* in  = second ? in1 : in0;
    const int* nbr   = second ? nbr1 : nbr0;
    const float* Wg  = second ? Wg1 : Wg0;
    float* out       = second ? out1 : out0;
    int bni          = second ? bni1 : bni0;

    const float4* Wg4 = (const float4*)Wg;
    float4* Wl4 = (float4*)Wl;
    for (int t = tid; t < 9 * CI * COUT / 4; t += 256) Wl4[t] = Wg4[t];
    if (tid < COUT) {
        float g = gamma[bni * COUT + tid], bt = beta[bni * COUT + tid];
        float m = mean[bni * COUT + tid], v = var[bni * COUT + tid];
        float s = g * rsqrtf(v + EPSV);
        sscale[tid] = s;
        sshift[tid] = bt - m * s;
    }
    __syncthreads();

    int ib = second ? (int)blockIdx.x - nblk : (int)blockIdx.x;
    int i = ib * 256 + tid;
    if (i >= n) return;

    int jall[9];
#pragma unroll
    for (int k = 0; k < 9; ++k) jall[k] = nbr[(size_t)k * n + i];

    float acc[COUT];
#pragma unroll
    for (int c = 0; c < COUT; ++c) acc[c] = 0.f;

#pragma unroll
    for (int k = 0; k < 9; ++k) {
        int j = jall[k];
        float sel = (j >= 0) ? 1.f : 0.f;
        int jc = (j >= 0) ? j : 0;
        const float4* f4 = (const float4*)(in + (size_t)jc * CI);
#pragma unroll
        for (int q = 0; q < CI / 4; ++q) {
            float4 v = f4[q];
            v.x *= sel; v.y *= sel; v.z *= sel; v.w *= sel;
            const float* w = &Wl[(k * CI + q * 4) * COUT];
#pragma unroll
            for (int c4 = 0; c4 < COUT / 4; ++c4) {
                float4 w0 = *(const float4*)&w[0 * COUT + c4 * 4];
                float4 w1 = *(const float4*)&w[1 * COUT + c4 * 4];
                float4 w2 = *(const float4*)&w[2 * COUT + c4 * 4];
                float4 w3 = *(const float4*)&w[3 * COUT + c4 * 4];
                acc[c4 * 4 + 0] += v.x * w0.x + v.y * w1.x + v.z * w2.x + v.w * w3.x;
                acc[c4 * 4 + 1] += v.x * w0.y + v.y * w1.y + v.z * w2.y + v.w * w3.y;
                acc[c4 * 4 + 2] += v.x * w0.z + v.y * w1.z + v.z * w2.z + v.w * w3.z;
                acc[c4 * 4 + 3] += v.x * w0.w + v.y * w1.w + v.z * w2.w + v.w * w3.w;
            }
        }
    }

#pragma unroll
    for (int c = 0; c < COUT; ++c) {
        float y = acc[c] * sscale[c] + sshift[c];
        acc[c] = (y >= 0.f) ? y : NEGS * y;
    }
    float4* o = (float4*)(out + (size_t)i * COUT);
#pragma unroll
    for (int c4 = 0; c4 < COUT / 4; ++c4)
        o[c4] = make_float4(acc[4 * c4 + 0], acc[4 * c4 + 1], acc[4 * c4 + 2], acc[4 * c4 + 3]);
}

__global__ __launch_bounds__(256) void add_res(float* __restrict__ out,
                                               const float* __restrict__ s, int n4) {
    int i = blockIdx.x * 256 + threadIdx.x;
    if (i < n4) {
        float4 a = ((const float4*)out)[i];
        float4 b = ((const float4*)s)[i];
        a.x += b.x; a.y += b.y; a.z += b.z; a.w += b.w;
        ((float4*)out)[i] = a;
    }
}

extern "C" void kernel_launch(void* const* d_in, const int* in_sizes, int n_in,
                              void* d_out, int out_size, void* d_ws, size_t ws_size,
                              hipStream_t stream) {
    const float* feats = (const float*)d_in[0];
    const int* coords  = (const int*)d_in[1];
    const float* W1    = (const float*)d_in[2];
    const float* W2    = (const float*)d_in[3];
    const float* W3    = (const float*)d_in[4];
    const float* W4    = (const float*)d_in[5];
    const float* gamma = (const float*)d_in[6];
    const float* beta  = (const float*)d_in[7];
    const float* mean  = (const float*)d_in[8];
    const float* var   = (const float*)d_in[9];

    int n = in_sizes[0] / CIN;  // 200000

    char* ws = (char*)d_ws;
    size_t nbrBytes  = (size_t)9 * n * sizeof(int);
    size_t featBytes = (size_t)n * COUT * sizeof(float);
    size_t gridBytes = (size_t)NB * DD * HH * WD * sizeof(int);

    int* nbr133 = (int*)ws;
    int* nbr313 = (int*)(ws + nbrBytes);
    char* fbase = ws + 2 * nbrBytes;
    float* s1 = (float*)fbase;                      // conv1 out
    float* s2 = (float*)(fbase + featBytes);        // shortcut
    float* r1 = (float*)(fbase + 2 * featBytes);    // conv3 out
    int* grid = (int*)fbase;  // overlaps s1/s2 region; grid dead after build_nbr

    int nblk = (n + 255) / 256;

    hipMemsetAsync(grid, 0xFF, gridBytes, stream);
    scatter_grid<<<nblk, 256, 0, stream>>>(coords, grid, n);
    build_nbr<<<nblk, 256, 0, stream>>>(coords, grid, nbr133, nbr313, n);

    // conv1 (feats->s1, bn0) || conv3 (feats->r1, bn2)
    conv_pair<CIN><<<2 * nblk, 256, 0, stream>>>(
        feats, nbr133, W1, s1, 0,
        feats, nbr313, W3, r1, 2,
        gamma, beta, mean, var, n, nblk);

    // conv2 (s1->s2, bn1) || conv4 (r1->d_out, bn3)
    conv_pair<COUT><<<2 * nblk, 256, 0, stream>>>(
        s1, nbr313, W2, s2, 1,
        r1, nbr133, W4, (float*)d_out, 3,
        gamma, beta, mean, var, n, nblk);

    // d_out += s2 (resA + shortcut)
    int n4 = n * COUT / 4;
    add_res<<<(n4 + 255) / 256, 256, 0, stream>>>((float*)d_out, s2, n4);
}

// Round 3
// 202.298 us; speedup vs baseline: 2.0756x; 2.0756x over previous
//
#include <hip/hip_runtime.h>

#define NB 2
#define DD 480
#define HH 360
#define WD 32
#define CIN 16
#define COUT 32
#define EPSV 1e-5f
#define NEGS 0.01f

__global__ __launch_bounds__(256) void scatter_grid(const int* __restrict__ coords,
                                                    int* __restrict__ grid, int n) {
    int i = blockIdx.x * 256 + threadIdx.x;
    if (i >= n) return;
    int b = coords[i * 4 + 0];
    int z = coords[i * 4 + 1];
    int y = coords[i * 4 + 2];
    int x = coords[i * 4 + 3];
    grid[(((size_t)b * DD + z) * HH + y) * WD + x] = i;
}

// Compact non-center valid taps per point. Center tap (k=4) is always the
// point itself (grid[coords[i]] == i), handled implicitly by the conv.
// ent entries: (k<<24) | j   (j < 2^24 since n = 200000)
__global__ __launch_bounds__(256) void build_nbr_compact(
    const int* __restrict__ coords, const int* __restrict__ grid,
    int* __restrict__ cnt133, int* __restrict__ ent133,
    int* __restrict__ cnt313, int* __restrict__ ent313, int n) {
    int i = blockIdx.x * 256 + threadIdx.x;
    if (i >= n) return;
    int b = coords[i * 4 + 0];
    int z = coords[i * 4 + 1];
    int y = coords[i * 4 + 2];
    int x = coords[i * 4 + 3];
    size_t base_b = (size_t)b * DD;
    int c1 = 0, c2 = 0;
#pragma unroll
    for (int k = 0; k < 9; ++k) {
        if (k == 4) continue;
        int d0 = k / 3 - 1;  // dy for 133, dz for 313
        int dx = k % 3 - 1;
        int nx = x + dx;
        bool xok = (nx >= 0) && (nx < WD);
        int ny = y + d0;
        if (xok && ny >= 0 && ny < HH) {
            int j = grid[((base_b + z) * HH + ny) * WD + nx];
            if (j >= 0) { ent133[(size_t)c1 * n + i] = (k << 24) | j; ++c1; }
        }
        int nz = z + d0;
        if (xok && nz >= 0 && nz < DD) {
            int j = grid[((base_b + nz) * HH + y) * WD + nx];
            if (j >= 0) { ent313[(size_t)c2 * n + i] = (k << 24) | j; ++c2; }
        }
    }
    cnt133[i] = c1;
    cnt313[i] = c2;
}

// Fused pair of independent sparse convs: blocks [0,nblk) do conv "0",
// blocks [nblk,2*nblk) do conv "1". Center tap dense + compacted extras.
template <int CI>
__global__ __launch_bounds__(256) void conv_pair(
    const float* __restrict__ in0, const int* __restrict__ cnt0,
    const int* __restrict__ ent0, const float* __restrict__ Wg0,
    float* __restrict__ out0, int bni0,
    const float* __restrict__ in1, const int* __restrict__ cnt1,
    const int* __restrict__ ent1, const float* __restrict__ Wg1,
    float* __restrict__ out1, int bni1,
    const float* __restrict__ gamma, const float* __restrict__ beta,
    const float* __restrict__ mean, const float* __restrict__ var,
    int n, int nblk) {
    constexpr int WROW = CI * COUT;  // floats per tap
    constexpr int WPAD = WROW + 4;   // +4 floats: runtime-k lane reads hit distinct banks
    __shared__ float Wl[9 * WPAD];
    __shared__ float sscale[COUT];
    __shared__ float sshift[COUT];
    int tid = threadIdx.x;
    bool second = (int)blockIdx.x >= nblk;
    const float* in  = second ? in1 : in0;
    const int* cnt   = second ? cnt1 : cnt0;
    const int* ent   = second ? ent1 : ent0;
    const float* Wg  = second ? Wg1 : Wg0;
    float* out       = second ? out1 : out0;
    int bni          = second ? bni1 : bni0;

    for (int t = tid; t < 9 * WROW / 4; t += 256) {
        int k = t / (WROW / 4);
        int r = t % (WROW / 4);
        ((float4*)&Wl[k * WPAD])[r] = ((const float4*)Wg)[t];
    }
    if (tid < COUT) {
        float g = gamma[bni * COUT + tid], bt = beta[bni * COUT + tid];
        float m = mean[bni * COUT + tid], v = var[bni * COUT + tid];
        float s = g * rsqrtf(v + EPSV);
        sscale[tid] = s;
        sshift[tid] = bt - m * s;
    }
    __syncthreads();

    int ib = second ? (int)blockIdx.x - nblk : (int)blockIdx.x;
    int i = ib * 256 + tid;
    if (i >= n) return;

    float acc[COUT];
#pragma unroll
    for (int c = 0; c < COUT; ++c) acc[c] = 0.f;

    // ---- center tap: neighbor index is i itself; wave-uniform weight reads
    {
        const float4* f4 = (const float4*)(in + (size_t)i * CI);
        const float* w0b = &Wl[4 * WPAD];
#pragma unroll
        for (int q = 0; q < CI / 4; ++q) {
            float4 v = f4[q];
            const float* w = w0b + q * 4 * COUT;
#pragma unroll
            for (int c4 = 0; c4 < COUT / 4; ++c4) {
                float4 w0 = *(const float4*)&w[0 * COUT + c4 * 4];
                float4 w1 = *(const float4*)&w[1 * COUT + c4 * 4];
                float4 w2 = *(const float4*)&w[2 * COUT + c4 * 4];
                float4 w3 = *(const float4*)&w[3 * COUT + c4 * 4];
                acc[c4 * 4 + 0] += v.x * w0.x + v.y * w1.x + v.z * w2.x + v.w * w3.x;
                acc[c4 * 4 + 1] += v.x * w0.y + v.y * w1.y + v.z * w2.y + v.w * w3.y;
                acc[c4 * 4 + 2] += v.x * w0.z + v.y * w1.z + v.z * w2.z + v.w * w3.z;
                acc[c4 * 4 + 3] += v.x * w0.w + v.y * w1.w + v.z * w2.w + v.w * w3.w;
            }
        }
    }

    // ---- rare extras: avg ~0.14 per point
    int cn = cnt[i];
    for (int m = 0; m < cn; ++m) {
        int e = ent[(size_t)m * n + i];
        int k = e >> 24;
        int j = e & 0xFFFFFF;
        const float4* f4 = (const float4*)(in + (size_t)j * CI);
        const float* wkb = &Wl[k * WPAD];
#pragma unroll
        for (int q = 0; q < CI / 4; ++q) {
            float4 v = f4[q];
            const float* w = wkb + q * 4 * COUT;
#pragma unroll
            for (int c4 = 0; c4 < COUT / 4; ++c4) {
                float4 w0 = *(const float4*)&w[0 * COUT + c4 * 4];
                float4 w1 = *(const float4*)&w[1 * COUT + c4 * 4];
                float4 w2 = *(const float4*)&w[2 * COUT + c4 * 4];
                float4 w3 = *(const float4*)&w[3 * COUT + c4 * 4];
                acc[c4 * 4 + 0] += v.x * w0.x + v.y * w1.x + v.z * w2.x + v.w * w3.x;
                acc[c4 * 4 + 1] += v.x * w0.y + v.y * w1.y + v.z * w2.y + v.w * w3.y;
                acc[c4 * 4 + 2] += v.x * w0.z + v.y * w1.z + v.z * w2.z + v.w * w3.z;
                acc[c4 * 4 + 3] += v.x * w0.w + v.y * w1.w + v.z * w2.w + v.w * w3.w;
            }
        }
    }

#pragma unroll
    for (int c = 0; c < COUT; ++c) {
        float y = acc[c] * sscale[c] + sshift[c];
        acc[c] = (y >= 0.f) ? y : NEGS * y;
    }
    float4* o = (float4*)(out + (size_t)i * COUT);
#pragma unroll
    for (int c4 = 0; c4 < COUT / 4; ++c4)
        o[c4] = make_float4(acc[4 * c4 + 0], acc[4 * c4 + 1], acc[4 * c4 + 2], acc[4 * c4 + 3]);
}

__global__ __launch_bounds__(256) void add_res(float* __restrict__ out,
                                               const float* __restrict__ s, int n4) {
    int i = blockIdx.x * 256 + threadIdx.x;
    if (i < n4) {
        float4 a = ((const float4*)out)[i];
        float4 b = ((const float4*)s)[i];
        a.x += b.x; a.y += b.y; a.z += b.z; a.w += b.w;
        ((float4*)out)[i] = a;
    }
}

extern "C" void kernel_launch(void* const* d_in, const int* in_sizes, int n_in,
                              void* d_out, int out_size, void* d_ws, size_t ws_size,
                              hipStream_t stream) {
    const float* feats = (const float*)d_in[0];
    const int* coords  = (const int*)d_in[1];
    const float* W1    = (const float*)d_in[2];
    const float* W2    = (const float*)d_in[3];
    const float* W3    = (const float*)d_in[4];
    const float* W4    = (const float*)d_in[5];
    const float* gamma = (const float*)d_in[6];
    const float* beta  = (const float*)d_in[7];
    const float* mean  = (const float*)d_in[8];
    const float* var   = (const float*)d_in[9];

    int n = in_sizes[0] / CIN;  // 200000

    char* ws = (char*)d_ws;
    size_t cntBytes  = (size_t)n * sizeof(int);
    size_t entBytes  = (size_t)8 * n * sizeof(int);
    size_t featBytes = (size_t)n * COUT * sizeof(float);
    size_t gridBytes = (size_t)NB * DD * HH * WD * sizeof(int);

    int* cnt133 = (int*)ws;
    int* cnt313 = (int*)(ws + cntBytes);
    int* ent133 = (int*)(ws + 2 * cntBytes);
    int* ent313 = (int*)(ws + 2 * cntBytes + entBytes);
    char* fbase = ws + 2 * cntBytes + 2 * entBytes;
    float* s1 = (float*)fbase;                      // conv1 out
    float* s2 = (float*)(fbase + featBytes);        // shortcut
    float* r1 = (float*)(fbase + 2 * featBytes);    // conv3 out
    int* grid = (int*)fbase;  // overlaps s1/s2 region; grid dead after build_nbr

    int nblk = (n + 255) / 256;

    hipMemsetAsync(grid, 0xFF, gridBytes, stream);
    scatter_grid<<<nblk, 256, 0, stream>>>(coords, grid, n);
    build_nbr_compact<<<nblk, 256, 0, stream>>>(coords, grid, cnt133, ent133,
                                                cnt313, ent313, n);

    // conv1 (feats->s1, bn0) || conv3 (feats->r1, bn2)
    conv_pair<CIN><<<2 * nblk, 256, 0, stream>>>(
        feats, cnt133, ent133, W1, s1, 0,
        feats, cnt313, ent313, W3, r1, 2,
        gamma, beta, mean, var, n, nblk);

    // conv2 (s1->s2, bn1) || conv4 (r1->d_out, bn3)
    conv_pair<COUT><<<2 * nblk, 256, 0, stream>>>(
        s1, cnt313, ent313, W2, s2, 1,
        r1, cnt133, ent133, W4, (float*)d_out, 3,
        gamma, beta, mean, var, n, nblk);

    // d_out += s2 (resA + shortcut)
    int n4 = n * COUT / 4;
    add_res<<<(n4 + 255) / 256, 256, 0, stream>>>((float*)d_out, s2, n4);
}